// Round 6
// baseline (672.259 us; speedup 1.0000x reference)
//
#include <hip/hip_runtime.h>
#include <math.h>

#define VOCAB 50000
#define EE 301
#define DD 25
#define SEQ 128
#define NC 5
#define NCOL 650   // 625 x@A columns + 25 x@W columns
#define ROWF 656   // padded row stride

// ---------------- Bmat[e][c]: exact copies, NO folding ----------------
// c<625: A[i=c/25][e][d=c%25]; 625<=c<650: W[e][c-625]; else 0
__global__ __launch_bounds__(256) void build_B(
    const float* __restrict__ A, const float* __restrict__ W,
    float* __restrict__ Bmat)
{
    int e = blockIdx.x;
    for (int c = threadIdx.x; c < ROWF; c += 256) {
        float v = 0.f;
        if (c < 625) {
            int i = c / 25, d = c % 25;
            v = A[((size_t)i * EE + e) * DD + d];
        } else if (c < NCOL) {
            v = W[(size_t)e * DD + (c - 625)];
        }
        Bmat[(size_t)e * ROWF + c] = v;
    }
}

// ---------------- T = emb @ Bmat (fp32, ascending-e fmaf = OpenBLAS sgemm) ----------------
#define TM 64
#define TN 64
#define KC 16
__global__ __launch_bounds__(256) void gemm_T(
    const float* __restrict__ emb,   // [VOCAB][301] (emb_table incl. ones col)
    const float* __restrict__ Bmat,  // [301][ROWF]
    float* __restrict__ T)           // [VOCAB][ROWF]
{
    __shared__ float As[KC][TM + 1];
    __shared__ float Bs[KC][TN];
    int tid = threadIdx.x;
    int tx = tid & 15, ty = tid >> 4;
    int m0 = blockIdx.x * TM;
    int n0 = blockIdx.y * TN;
    float acc[4][4];
#pragma unroll
    for (int a = 0; a < 4; ++a)
#pragma unroll
        for (int c = 0; c < 4; ++c) acc[a][c] = 0.f;

    for (int k0 = 0; k0 < EE; k0 += KC) {
#pragma unroll
        for (int p = 0; p < 4; ++p) {
            int idx = tid + p * 256;
            int ml = idx >> 4, kl = idx & 15;
            int m = m0 + ml, k = k0 + kl;
            As[kl][ml] = (m < VOCAB && k < EE) ? emb[(size_t)m * EE + k] : 0.f;
        }
#pragma unroll
        for (int p = 0; p < 4; ++p) {
            int idx = tid + p * 256;
            int kl = idx >> 6, nl = idx & 63;
            int k = k0 + kl, n = n0 + nl;
            Bs[kl][nl] = (k < EE && n < NCOL) ? Bmat[(size_t)k * ROWF + n] : 0.f;
        }
        __syncthreads();
#pragma unroll
        for (int kk = 0; kk < KC; ++kk) {   // global k = k0+kk strictly ascending
            float av[4], bv[4];
#pragma unroll
            for (int r = 0; r < 4; ++r) av[r] = As[kk][ty * 4 + r];
#pragma unroll
            for (int r = 0; r < 4; ++r) bv[r] = Bs[kk][tx * 4 + r];
#pragma unroll
            for (int a = 0; a < 4; ++a)
#pragma unroll
                for (int c = 0; c < 4; ++c)
                    acc[a][c] = fmaf(av[a], bv[c], acc[a][c]);
        }
        __syncthreads();
    }
#pragma unroll
    for (int a = 0; a < 4; ++a) {
        int m = m0 + ty * 4 + a;
        int n = n0 + tx * 4;
        if (m < VOCAB && n + 3 < ROWF) {
            *(float4*)(&T[(size_t)m * ROWF + n]) =
                make_float4(acc[a][0], acc[a][1], acc[a][2], acc[a][3]);
        }
    }
}

// ---------------- scan: np c_einsum 'bid,bd->bi' semantics ----------------
// a[b,i]: if (b%4==0 && i%4==0) [both CPU row ptrs 16B-aligned -> SSE path]:
//   4 partials p[l] = sum_{j<24, j%4==l} round(T_j*h_j)  (rounded add each),
//   a = ((p0+p2)+(p1+p3)) + round(T_24*h_24)
// else: scalar chain a += round(T_j*h_j), j ascending, NO fma.
// lin = ((x@W) + (h@V)) + b; pre = a + lin; h = tanh (fp64->fp32).
__global__ __launch_bounds__(256) void rnn_scan_np3(
    const int*   __restrict__ words,  // [B][SEQ]
    const float* __restrict__ T,      // [VOCAB][ROWF]
    const float* __restrict__ V,      // [DD][DD]
    const float* __restrict__ bvec,   // [DD]
    const float* __restrict__ outW,   // [NC][DD]
    const float* __restrict__ outB,   // [NC]
    float* __restrict__ out,          // [B][NC]
    int B)
{
    __shared__ float hs[8][DD];
    __shared__ float Vs[DD * DD];

    int tid = threadIdx.x;
    int bl = tid >> 5, i = tid & 31;
    int b  = blockIdx.x * 8 + bl;
    bool act = (i < DD) && (b < B);
    int ii = (i < DD) ? i : (DD - 1);
    int bsafe = (b < B) ? b : 0;
    const int* wr = words + (size_t)bsafe * SEQ;

    for (int idx = tid; idx < DD * DD; idx += 256) Vs[idx] = V[idx];
    if (tid < 8 * DD) { int bb = tid / DD, j = tid % DD; hs[bb][j] = (j == DD - 1) ? 1.f : 0.f; }
    float bi = (i < DD) ? bvec[i] : 0.f;
    __syncthreads();

    float Vcol[DD];
#pragma unroll
    for (int j = 0; j < DD; ++j) Vcol[j] = Vs[j * DD + ii];

    bool sse = ((b & 3) == 0) && ((i & 3) == 0);

    for (int t = 0; t < SEQ; ++t) {
        int w = wr[t];
        const float* Tr = T + (size_t)w * ROWF + ii * DD;
        float qv = T[(size_t)w * ROWF + 625 + ii];

        float hr[DD];
#pragma unroll
        for (int j = 0; j < DD; ++j) hr[j] = hs[bl][j];

        float a;
        if (sse) {
            float p0 = 0.f, p1 = 0.f, p2 = 0.f, p3 = 0.f;
#pragma unroll
            for (int j = 0; j < 24; j += 4) {
                p0 = __fadd_rn(p0, __fmul_rn(Tr[j],     hr[j]));
                p1 = __fadd_rn(p1, __fmul_rn(Tr[j + 1], hr[j + 1]));
                p2 = __fadd_rn(p2, __fmul_rn(Tr[j + 2], hr[j + 2]));
                p3 = __fadd_rn(p3, __fmul_rn(Tr[j + 3], hr[j + 3]));
            }
            float s02 = __fadd_rn(p0, p2);
            float s13 = __fadd_rn(p1, p3);
            a = __fadd_rn(s02, s13);
            a = __fadd_rn(a, __fmul_rn(Tr[24], hr[24]));      // scalar tail j=24
        } else {
            a = 0.f;
#pragma unroll
            for (int j = 0; j < DD; ++j)
                a = __fadd_rn(a, __fmul_rn(Tr[j], hr[j]));
        }

        float r2 = 0.f;                                        // h@V: BLAS k-seq FMA
#pragma unroll
        for (int j = 0; j < DD; ++j)
            r2 = fmaf(hr[j], Vcol[j], r2);

        float lin = __fadd_rn(__fadd_rn(qv, r2), bi);          // (xW + hV) + b
        float pre = __fadd_rn(a, lin);                         // a + lin
        float hnew = act ? (float)tanh((double)pre) : 0.f;

        __syncthreads();
        if (act) hs[bl][i] = hnew;
        __syncthreads();
    }

    // logits = h @ out_W.T + out_b ; sigmoid  (BLAS k-seq FMA)
    if (i < NC && b < B) {
        float acc = 0.f;
#pragma unroll
        for (int j = 0; j < DD; ++j)
            acc = fmaf(hs[bl][j], outW[i * DD + j], acc);
        float l = __fadd_rn(acc, outB[i]);
        out[(size_t)b * NC + i] = (float)(1.0 / (1.0 + exp(-(double)l)));
    }
}

extern "C" void kernel_launch(void* const* d_in, const int* in_sizes, int n_in,
                              void* d_out, int out_size, void* d_ws, size_t ws_size,
                              hipStream_t stream)
{
    const int*   words = (const int*)d_in[0];
    const float* emb   = (const float*)d_in[2];
    const float* A     = (const float*)d_in[3];
    const float* W     = (const float*)d_in[4];
    const float* V     = (const float*)d_in[5];
    const float* bias  = (const float*)d_in[6];
    const float* outW  = (const float*)d_in[7];
    const float* outB  = (const float*)d_in[8];
    float* out = (float*)d_out;
    int B = in_sizes[0] / SEQ;

    float* Bmat = (float*)d_ws;                        // 301*656*4 ≈ 0.79 MB
    float* T    = (float*)((char*)d_ws + (1 << 20));   // 50000*656*4 ≈ 131.2 MB

    build_B<<<EE, 256, 0, stream>>>(A, W, Bmat);
    gemm_T<<<dim3((VOCAB + TM - 1) / TM, (ROWF + TN - 1) / TN), 256, 0, stream>>>(emb, Bmat, T);
    rnn_scan_np3<<<(B + 7) / 8, 256, 0, stream>>>(words, T, V, bias, outW, outB, out, B);
}